// Round 1
// baseline (523.525 us; speedup 1.0000x reference)
//
#include <hip/hip_runtime.h>
#include <math.h>

#define NB 256      // events
#define KNN 8

typedef float v2f __attribute__((ext_vector_type(2)));

__device__ __forceinline__ float elu_f(float x) {
    return x > 0.f ? x : __expf(x) - 1.f;
}

// ---- sorting-network primitives on u32 keys -------------------------------
// key = (bits(dv) & ~511) | global_row_idx, dv >= 0 so raw-bit order == float
// order. Truncation to 512 ulp, tie-break lower-index-wins (same policy as
// the validated ce8 version; dv is shifted by +|dst|^2, a monotone transform).
__device__ __forceinline__ void cex(unsigned& a, unsigned& b) {
    unsigned lo = min(a, b), hi = max(a, b);
    a = lo; b = hi;
}

// Batcher odd-even mergesort, 8 elements, 19 CE.
__device__ __forceinline__ void sort8(unsigned* s) {
    cex(s[0], s[1]); cex(s[2], s[3]); cex(s[4], s[5]); cex(s[6], s[7]);
    cex(s[0], s[2]); cex(s[1], s[3]); cex(s[4], s[6]); cex(s[5], s[7]);
    cex(s[1], s[2]); cex(s[5], s[6]);
    cex(s[0], s[4]); cex(s[1], s[5]); cex(s[2], s[6]); cex(s[3], s[7]);
    cex(s[2], s[4]); cex(s[3], s[5]);
    cex(s[1], s[2]); cex(s[3], s[4]); cex(s[5], s[6]);
}

// v asc top-8, s asc 8 candidates -> v = 8 smallest of union, ascending.
// min(v[i], s[7-i]) keeps the 8 smallest (bitonic lower half), then a
// 3-stage bitonic clean restores ascending order. 8 + 24 ops.
__device__ __forceinline__ void merge8(unsigned* v, const unsigned* s) {
#pragma unroll
    for (int i = 0; i < 8; i++) v[i] = min(v[i], s[7 - i]);
    cex(v[0], v[4]); cex(v[1], v[5]); cex(v[2], v[6]); cex(v[3], v[7]);
    cex(v[0], v[2]); cex(v[1], v[3]); cex(v[4], v[6]); cex(v[5], v[7]);
    cex(v[0], v[1]); cex(v[2], v[3]); cex(v[4], v[5]); cex(v[6], v[7]);
}

// ================= fused encoder (+ conv-side linear precomputes) =========
template<int FIN, int EXTRA>
__device__ void encode64_body(const float* __restrict__ x,
    const float* __restrict__ W1, const float* __restrict__ b1,
    const float* __restrict__ W2, const float* __restrict__ b2,
    const float* __restrict__ conv_W, const float* __restrict__ conv_b,
    float* __restrict__ enc, float* __restrict__ e1, float* __restrict__ e2,
    int blk, float* smem)
{
    float* sx  = smem;              // up to 64*30
    float* sW1 = sx + 64 * 30;      // up to 30*32
    float* sW2 = sW1 + 30 * 32;     // 1024
    float* sWe = sW2 + 1024;        // 1024
    float* sb1 = sWe + 1024;
    float* sb2 = sb1 + 32;
    float* sbe = sb2 + 32;
    float* sh  = sbe + 32;          // 2048
    int tid = threadIdx.x;
    for (int i = tid; i < FIN * 32; i += 256) sW1[i] = W1[i];
    for (int i = tid; i < 1024; i += 256) sW2[i] = W2[i];
    if (EXTRA == 1) for (int i = tid; i < 1024; i += 256) sWe[i] = conv_W[1024 + i];
    if (EXTRA == 2) for (int i = tid; i < 1024; i += 256) sWe[i] = conv_W[i] - conv_W[1024 + i];
    if (tid < 32) {
        sb1[tid] = b1[tid]; sb2[tid] = b2[tid];
        sbe[tid] = (EXTRA == 2) ? conv_b[tid] : 0.f;
    }
    size_t node0 = (size_t)blk * 64;
    for (int i = tid; i < 64 * FIN; i += 256) sx[i] = x[node0 * FIN + i];
    __syncthreads();
    int g = tid >> 5, c = tid & 31;
    float o[8];
#pragma unroll
    for (int j = 0; j < 8; j++) {
        int n = g * 8 + j;
        float a = sb1[c];
#pragma unroll
        for (int f = 0; f < FIN; f++) a = fmaf(sx[n * FIN + f], sW1[f * 32 + c], a);
        sh[n * 32 + c] = elu_f(a);
    }
    __syncthreads();
#pragma unroll
    for (int j = 0; j < 8; j++) {
        int n = g * 8 + j;
        float a = sb2[c];
#pragma unroll
        for (int k = 0; k < 32; k++) a = fmaf(sh[n * 32 + k], sW2[k * 32 + c], a);
        o[j] = elu_f(a);
        enc[(node0 + n) * 32 + c] = o[j];
    }
    if (EXTRA == 0) return;
    __syncthreads();
#pragma unroll
    for (int j = 0; j < 8; j++) sh[(g * 8 + j) * 32 + c] = o[j];
    __syncthreads();
#pragma unroll
    for (int j = 0; j < 8; j++) {
        int n = g * 8 + j;
        float a = sbe[c];
#pragma unroll
        for (int d = 0; d < 32; d++) a = fmaf(sh[n * 32 + d], sWe[d * 32 + c], a);
        size_t off = (node0 + n) * 32 + c;
        e1[off] = a;
        if (EXTRA == 2) e2[off] = a;
    }
}

// 4352 blocks: sv(256) | trk(2048) | pfc(2048)
__global__ __launch_bounds__(256) void encode_all_kernel(
    const float* __restrict__ x_sv, const float* __restrict__ x_trk, const float* __restrict__ x_pfc,
    const float* __restrict__ sv_W1, const float* __restrict__ sv_b1,
    const float* __restrict__ sv_W2, const float* __restrict__ sv_b2,
    const float* __restrict__ trk_W1, const float* __restrict__ trk_b1,
    const float* __restrict__ trk_W2, const float* __restrict__ trk_b2,
    const float* __restrict__ pfc_W1, const float* __restrict__ pfc_b1,
    const float* __restrict__ pfc_W2, const float* __restrict__ pfc_b2,
    const float* __restrict__ conv_W, const float* __restrict__ conv_b,
    float* __restrict__ sv_enc, float* __restrict__ trk_enc, float* __restrict__ pfc_enc,
    float* __restrict__ Y1, float* __restrict__ Y2,
    float* __restrict__ f1, float* __restrict__ f2)
{
    __shared__ float smem[64*30 + 30*32 + 1024 + 1024 + 96 + 2048];
    int bid = blockIdx.x;
    if (bid < 256)
        encode64_body<14, 1>(x_sv, sv_W1, sv_b1, sv_W2, sv_b2, conv_W, conv_b,
                             sv_enc, Y1, nullptr, bid, smem);
    else if (bid < 2304)
        encode64_body<30, 2>(x_trk, trk_W1, trk_b1, trk_W2, trk_b2, conv_W, conv_b,
                             trk_enc, f1, f2, bid - 256, smem);
    else
        encode64_body<10, 1>(x_pfc, pfc_W1, pfc_b1, pfc_W2, pfc_b2, conv_W, conv_b,
                             pfc_enc, Y2, nullptr, bid - 2304, smem);
}

// ================= kNN =====================================================
__device__ __forceinline__ void load_xd(const float4* xi, v2f* xd) {
#pragma unroll
    for (int q = 0; q < 8; q++) {
        float4 v = xi[q];
        xd[2*q]   = (v2f){v.x, v.y};
        xd[2*q+1] = (v2f){v.z, v.w};
    }
}

__device__ __forceinline__ float norm32(const v2f* xd) {
    v2f A = {0.f, 0.f}, B = {0.f, 0.f};
#pragma unroll
    for (int q = 0; q < 8; q++) {
        A = __builtin_elementwise_fma(xd[2*q],   xd[2*q],   A);
        B = __builtin_elementwise_fma(xd[2*q+1], xd[2*q+1], B);
    }
    v2f S = A + B;
    return S.x + S.y;
}

template<int NR>
__device__ void stage_rows(const float* __restrict__ src_rows,
                           float4* s_src, float* s_nrm, int tid)
{
    const float4* s4 = (const float4*)src_rows;
    for (int i = tid; i < NR * 8; i += 256) s_src[i] = s4[i];
    __syncthreads();
    for (int s = tid; s < NR; s += 256) {
        float a = 0.f;
#pragma unroll
        for (int q = 0; q < 8; q++) {
            float4 v = s_src[s * 8 + q];
            a = fmaf(v.x, v.x, a); a = fmaf(v.y, v.y, a);
            a = fmaf(v.z, v.z, a); a = fmaf(v.w, v.w, a);
        }
        s_nrm[s] = a;
    }
    __syncthreads();
}

// pk-fma distance chains (fp32) with dst-norm folded into accumulator init
// (dv >= 0 so raw-bit unsigned order == distance order), batched 8-candidate
// sort + bitonic top-8 merge.
template<int NR>
__device__ void knn_scan_core(const float4* __restrict__ s_src, const float* __restrict__ s_nrm,
                              const v2f* xd0, const v2f* xd1, float nh0, float nh1,
                              unsigned* key0, unsigned* key1, int base)
{
    for (int s0 = 0; s0 < NR; s0 += 8) {
        unsigned c0[8], c1[8];
#pragma unroll
        for (int j = 0; j < 8; j++) {
            int s = s0 + j;
            v2f A01 = {nh0, 0.f}, A23 = {0.f, 0.f};
            v2f C01 = {nh1, 0.f}, C23 = {0.f, 0.f};
#pragma unroll
            for (int q = 0; q < 8; q++) {
                float4 v = s_src[s * 8 + q];
                v2f vxy = {v.x, v.y};
                v2f vzw = {v.z, v.w};
                A01 = __builtin_elementwise_fma(xd0[2*q],   vxy, A01);
                A23 = __builtin_elementwise_fma(xd0[2*q+1], vzw, A23);
                C01 = __builtin_elementwise_fma(xd1[2*q],   vxy, C01);
                C23 = __builtin_elementwise_fma(xd1[2*q+1], vzw, C23);
            }
            float nrm = s_nrm[s];
            v2f As = A01 + A23, Cs = C01 + C23;
            float dv0 = fmaf(-2.f, As.x + As.y, nrm);   // = nrm_src + nrm_dst - 2*dot
            float dv1 = fmaf(-2.f, Cs.x + Cs.y, nrm);
            c0[j] = (__float_as_uint(dv0) & 0xFFFFFE00u) | (unsigned)(base + s);
            c1[j] = (__float_as_uint(dv1) & 0xFFFFFE00u) | (unsigned)(base + s);
        }
        sort8(c0); merge8(key0, c0);
        sort8(c1); merge8(key1, c1);
    }
}

// split part (128 rows): per-dst partial sorted top-8 keys (global idx in key)
__device__ void knn_split_body(const float* __restrict__ src, const float* __restrict__ dst,
                               unsigned* __restrict__ pkey,
                               int b, int part, float4* s_src, float* s_nrm)
{
    int tid = threadIdx.x, lane = tid & 63, wave = tid >> 6;
    stage_rows<128>(src + ((size_t)b * 512 + part * 128) * 32, s_src, s_nrm, tid);

    int t0 = wave * 64 + lane, t1 = t0 + 256;
    v2f xd0[16], xd1[16];
    load_xd((const float4*)(dst + ((size_t)b * 512 + t0) * 32), xd0);
    load_xd((const float4*)(dst + ((size_t)b * 512 + t1) * 32), xd1);
    float nh0 = -0.5f * norm32(xd0);
    float nh1 = -0.5f * norm32(xd1);

    unsigned key0[8], key1[8];
#pragma unroll
    for (int k = 0; k < 8; k++) { key0[k] = 0xFFFFFFFFu; key1[k] = 0xFFFFFFFFu; }
    knn_scan_core<128>(s_src, s_nrm, xd0, xd1, nh0, nh1, key0, key1, part * 128);

    unsigned* p0 = pkey + ((size_t)b * 512 + t0) * 32 + part * 8;
    unsigned* p1 = pkey + ((size_t)b * 512 + t1) * 32 + part * 8;
#pragma unroll
    for (int k = 0; k < 8; k++) { p0[k] = key0[k]; p1[k] = key1[k]; }
}

// conv1 small (64 src rows): final top-8 idx (u16) directly
__device__ void knn_small_body(const float* __restrict__ src, const float* __restrict__ dst,
                               unsigned short* __restrict__ idx1_out,
                               int b, float4* s_src, float* s_nrm)
{
    int tid = threadIdx.x, lane = tid & 63, wave = tid >> 6;
    stage_rows<64>(src + (size_t)b * 64 * 32, s_src, s_nrm, tid);

    int t0 = wave * 64 + lane, t1 = t0 + 256;
    v2f xd0[16], xd1[16];
    load_xd((const float4*)(dst + ((size_t)b * 512 + t0) * 32), xd0);
    load_xd((const float4*)(dst + ((size_t)b * 512 + t1) * 32), xd1);
    float nh0 = -0.5f * norm32(xd0);
    float nh1 = -0.5f * norm32(xd1);

    unsigned key0[8], key1[8];
#pragma unroll
    for (int k = 0; k < 8; k++) { key0[k] = 0xFFFFFFFFu; key1[k] = 0xFFFFFFFFu; }
    knn_scan_core<64>(s_src, s_nrm, xd0, xd1, nh0, nh1, key0, key1, 0);

    for (int h = 0; h < 2; h++) {
        int t = h ? t1 : t0;
        const unsigned* kk = h ? key1 : key0;
        unsigned int* o32 = (unsigned int*)(idx1_out + ((size_t)b * 512 + t) * 8);
#pragma unroll
        for (int k = 0; k < 4; k++)
            o32[k] = (kk[2*k] & 511u) | ((kk[2*k+1] & 511u) << 16);
    }
}

// knn12: 1280 blocks. conv2 split: bid<1024 (part=bid>>8, e=bid&255).
// conv1 small: tail blocks.
__global__ __launch_bounds__(256, 4) void knn12_kernel(
    const float* __restrict__ sv_enc, const float* __restrict__ trk_enc,
    const float* __restrict__ pfc_enc,
    unsigned short* __restrict__ idx1_out,
    unsigned* __restrict__ pkey)
{
    __shared__ float4 s_src[128 * 8];
    __shared__ float  s_nrm[128];
    int bid = blockIdx.x;
    if (bid < 1024) knn_split_body(pfc_enc, trk_enc, pkey, bid & 255, bid >> 8, s_src, s_nrm);
    else            knn_small_body(sv_enc, trk_enc, idx1_out, bid - 1024, s_src, s_nrm);
}

__global__ __launch_bounds__(256, 4) void knn3_kernel(
    const float* __restrict__ f1, const float* __restrict__ f2,
    unsigned* __restrict__ pkey)
{
    __shared__ float4 s_src[128 * 8];
    __shared__ float  s_nrm[128];
    int bid = blockIdx.x;
    knn_split_body(f1, f2, pkey, bid & 255, bid >> 8, s_src, s_nrm);
}

// ================= gather helpers ==========================================
// merge 4 sorted partial key-lists (ascending part order) -> final 8 rows
__device__ __forceinline__ void merge_parts(const unsigned* __restrict__ pk_, int* rows)
{
    const uint4* pk = (const uint4*)pk_;
    uint4 a0 = pk[0], a1 = pk[1];
    unsigned v[8] = { a0.x, a0.y, a0.z, a0.w, a1.x, a1.y, a1.z, a1.w };
#pragma unroll
    for (int p = 1; p < 4; p++) {
        uint4 b0 = pk[2*p], b1 = pk[2*p+1];
        unsigned s[8] = { b0.x, b0.y, b0.z, b0.w, b1.x, b1.y, b1.z, b1.w };
        merge8(v, s);
    }
#pragma unroll
    for (int k = 0; k < 8; k++) rows[k] = (int)(v[k] & 511u);
}

__device__ __forceinline__ void maxgather(const float* __restrict__ Ybase,
                                          const int* rows, float4* m)
{
    const float4* Yb = (const float4*)Ybase;
    const float4* r0 = Yb + (size_t)rows[0] * 8;
#pragma unroll
    for (int q = 0; q < 8; q++) m[q] = r0[q];
#pragma unroll
    for (int k = 1; k < 8; k++) {
        const float4* rr = Yb + (size_t)rows[k] * 8;
#pragma unroll
        for (int q = 0; q < 8; q++) {
            float4 v = rr[q];
            m[q].x = fmaxf(m[q].x, v.x); m[q].y = fmaxf(m[q].y, v.y);
            m[q].z = fmaxf(m[q].z, v.z); m[q].w = fmaxf(m[q].w, v.w);
        }
    }
}

// g12: 1024 blocks. f holds Base (written by encode); in-place f=elu(f+maxY).
__global__ __launch_bounds__(256) void g12_kernel(
    const float* __restrict__ Y1, const unsigned short* __restrict__ idx1, float* __restrict__ f1,
    const float* __restrict__ Y2, const unsigned* __restrict__ pkey, float* __restrict__ f2)
{
    int bid = blockIdx.x;
    int tid = threadIdx.x;
    int rows[8];
    float* fp;
    const float* Yb;
    int t;
    if (bid < 512) {
        t = bid * 256 + tid;
        uint4 u = *(const uint4*)(idx1 + (size_t)t * 8);
        rows[0] = (int)(u.x & 0xffff); rows[1] = (int)(u.x >> 16);
        rows[2] = (int)(u.y & 0xffff); rows[3] = (int)(u.y >> 16);
        rows[4] = (int)(u.z & 0xffff); rows[5] = (int)(u.z >> 16);
        rows[6] = (int)(u.w & 0xffff); rows[7] = (int)(u.w >> 16);
        Yb = Y1 + (size_t)(t >> 9) * 64 * 32;
        fp = f1 + (size_t)t * 32;
    } else {
        t = (bid - 512) * 256 + tid;
        merge_parts(pkey + (size_t)t * 32, rows);
        Yb = Y2 + (size_t)(t >> 9) * 512 * 32;
        fp = f2 + (size_t)t * 32;
    }
    float4 m[8];
    maxgather(Yb, rows, m);
    float4* op = (float4*)fp;
#pragma unroll
    for (int q = 0; q < 8; q++) {
        float4 bv = op[q];
        float4 o;
        o.x = elu_f(bv.x + m[q].x); o.y = elu_f(bv.y + m[q].y);
        o.z = elu_f(bv.z + m[q].z); o.w = elu_f(bv.w + m[q].w);
        op[q] = o;
    }
}

// yb3: 4096 blocks: Y3 = f1@w2h (bid<2048) | B3 = f2@wd+bb
__global__ __launch_bounds__(256) void yb3_kernel(
    const float* __restrict__ f1, const float* __restrict__ f2,
    const float* __restrict__ conv_W, const float* __restrict__ conv_b,
    float* __restrict__ Y3, float* __restrict__ B3)
{
    __shared__ float sW[1024];
    __shared__ float sb[32];
    __shared__ float sx[8][32];
    int bid = blockIdx.x;
    int tid = threadIdx.x;
    int mode = (bid >= 2048);
    const float* X = mode ? f2 : f1;
    float* O = mode ? B3 : Y3;
    int rb = (mode ? bid - 2048 : bid) * 64;
    for (int i = tid; i < 1024; i += 256)
        sW[i] = mode ? (conv_W[i] - conv_W[1024 + i]) : conv_W[1024 + i];
    if (tid < 32) sb[tid] = mode ? conv_b[tid] : 0.f;
    int ln = tid >> 5, c = tid & 31;
    for (int p = 0; p < 8; p++) {
        __syncthreads();
        sx[ln][c] = X[(size_t)(rb + p * 8 + ln) * 32 + c];
        __syncthreads();
        float acc = sb[c];
#pragma unroll
        for (int d = 0; d < 32; d++) acc = fmaf(sx[ln][d], sW[d * 32 + c], acc);
        O[(size_t)(rb + p * 8 + ln) * 32 + c] = acc;
    }
}

// g3: 512 blocks. f3 rows in registers, reduced straight to pooled partials.
__global__ __launch_bounds__(256) void g3_kernel(
    const float* __restrict__ Y3, const float* __restrict__ B3,
    const unsigned* __restrict__ pkey,
    float* __restrict__ pool)
{
    __shared__ float sp[4][32];
    int bid = blockIdx.x;
    int tid = threadIdx.x, lane = tid & 63, wave = tid >> 6;
    int t = bid * 256 + tid;
    int e = t >> 9;
    int rows[8];
    merge_parts(pkey + (size_t)t * 32, rows);
    float4 m[8];
    maxgather(Y3 + (size_t)e * 512 * 32, rows, m);
    const float4* bp = (const float4*)(B3 + (size_t)t * 32);
    float4 r[8];
#pragma unroll
    for (int q = 0; q < 8; q++) {
        float4 bv = bp[q];
        r[q].x = elu_f(bv.x + m[q].x); r[q].y = elu_f(bv.y + m[q].y);
        r[q].z = elu_f(bv.z + m[q].z); r[q].w = elu_f(bv.w + m[q].w);
    }
    for (int off = 1; off < 64; off <<= 1) {
#pragma unroll
        for (int q = 0; q < 8; q++) {
            r[q].x += __shfl_xor(r[q].x, off);
            r[q].y += __shfl_xor(r[q].y, off);
            r[q].z += __shfl_xor(r[q].z, off);
            r[q].w += __shfl_xor(r[q].w, off);
        }
    }
    if (lane == 0) {
#pragma unroll
        for (int q = 0; q < 8; q++) {
            sp[wave][q*4+0] = r[q].x; sp[wave][q*4+1] = r[q].y;
            sp[wave][q*4+2] = r[q].z; sp[wave][q*4+3] = r[q].w;
        }
    }
    __syncthreads();
    if (tid < 32)
        pool[(size_t)bid * 32 + tid] = sp[0][tid] + sp[1][tid] + sp[2][tid] + sp[3][tid];
}

// final: 2 pooled partials per event + MLP + sigmoid + arange
__global__ __launch_bounds__(64) void final_kernel(
    const float* __restrict__ pool,
    const float* __restrict__ W1, const float* __restrict__ b1,
    const float* __restrict__ W2, const float* __restrict__ b2,
    float* __restrict__ outp)
{
    int b = blockIdx.x;
    int lane = threadIdx.x, c = lane & 31;
    __shared__ float sp[32];
    __shared__ float sh1[32];
    if (lane < 32)
        sp[c] = (pool[(size_t)(2*b) * 32 + c] + pool[(size_t)(2*b+1) * 32 + c]) * (1.0f / 512.0f);
    __syncthreads();
    if (lane < 32) {
        float h = b1[c];
#pragma unroll
        for (int d = 0; d < 32; d++) h = fmaf(sp[d], W1[d * 32 + c], h);
        sh1[c] = elu_f(h);
    }
    __syncthreads();
    if (lane == 0) {
        float o = b2[0];
#pragma unroll
        for (int d = 0; d < 32; d++) o = fmaf(sh1[d], W2[d], o);
        o = 1.f / (1.f + __expf(-o));
        outp[b] = o;
        outp[NB + b] = (float)b;
    }
}

extern "C" void kernel_launch(void* const* d_in, const int* in_sizes, int n_in,
                              void* d_out, int out_size, void* d_ws, size_t ws_size,
                              hipStream_t stream) {
    const float* x_sv  = (const float*)d_in[0];
    const float* x_trk = (const float*)d_in[1];
    const float* x_pfc = (const float*)d_in[2];
    const float* sv_W1  = (const float*)d_in[6];
    const float* sv_b1  = (const float*)d_in[7];
    const float* sv_W2  = (const float*)d_in[8];
    const float* sv_b2  = (const float*)d_in[9];
    const float* trk_W1 = (const float*)d_in[10];
    const float* trk_b1 = (const float*)d_in[11];
    const float* trk_W2 = (const float*)d_in[12];
    const float* trk_b2 = (const float*)d_in[13];
    const float* pfc_W1 = (const float*)d_in[14];
    const float* pfc_b1 = (const float*)d_in[15];
    const float* pfc_W2 = (const float*)d_in[16];
    const float* pfc_b2 = (const float*)d_in[17];
    const float* conv_W = (const float*)d_in[18];
    const float* conv_b = (const float*)d_in[19];
    const float* out_W1 = (const float*)d_in[20];
    const float* out_b1 = (const float*)d_in[21];
    const float* out_W2 = (const float*)d_in[22];
    const float* out_b2 = (const float*)d_in[23];

    float* ws = (float*)d_ws;
    const size_t SV_E  = (size_t)NB * 64 * 32;     //   524288
    const size_t TRK_E = (size_t)NB * 512 * 32;    //  4194304
    float* sv_enc  = ws;                           // pool aliases after knn12
    float* trk_enc = sv_enc + SV_E;                // B3 aliases after knn12
    float* pfc_enc = trk_enc + TRK_E;              // Y3 aliases after knn12
    float* f1      = pfc_enc + TRK_E;
    float* f2      = f1 + TRK_E;
    float* Y1      = f2 + TRK_E;                   // SV_E
    float* Y2      = Y1 + SV_E;                    // TRK_E
    unsigned* pkey = (unsigned*)(Y2 + TRK_E);      // NB*512*32 u32 (4 parts x 8)
    unsigned short* idx1 = (unsigned short*)(pkey + TRK_E);    // NB*512*8 u16
    float* Y3   = pfc_enc;   // pfc_enc dead after knn12
    float* B3   = trk_enc;   // trk_enc dead after knn12
    float* pool = sv_enc;    // sv_enc dead after knn12

    encode_all_kernel<<<4352, 256, 0, stream>>>(
        x_sv, x_trk, x_pfc,
        sv_W1, sv_b1, sv_W2, sv_b2,
        trk_W1, trk_b1, trk_W2, trk_b2,
        pfc_W1, pfc_b1, pfc_W2, pfc_b2,
        conv_W, conv_b,
        sv_enc, trk_enc, pfc_enc, Y1, Y2, f1, f2);

    knn12_kernel<<<1280, 256, 0, stream>>>(sv_enc, trk_enc, pfc_enc, idx1, pkey);
    g12_kernel<<<1024, 256, 0, stream>>>(Y1, idx1, f1, Y2, pkey, f2);

    yb3_kernel<<<4096, 256, 0, stream>>>(f1, f2, conv_W, conv_b, Y3, B3);
    knn3_kernel<<<1024, 256, 0, stream>>>(f1, f2, pkey);
    g3_kernel<<<512, 256, 0, stream>>>(Y3, B3, pkey, pool);

    final_kernel<<<NB, 64, 0, stream>>>(pool, out_W1, out_b1, out_W2, out_b2, (float*)d_out);
}

// Round 2
// 505.435 us; speedup vs baseline: 1.0358x; 1.0358x over previous
//
#include <hip/hip_runtime.h>
#include <math.h>

#define NB 256      // events
#define KNN 8

typedef float v2f __attribute__((ext_vector_type(2)));

__device__ __forceinline__ float elu_f(float x) {
    return x > 0.f ? x : __expf(x) - 1.f;
}

// ---- sorting-network primitives on u32 keys -------------------------------
// key = (bits(dv) & ~511) | global_row_idx, dv >= 0 so raw-bit order == float
// order. Truncation to 512 ulp, tie-break lower-index-wins (validated r1).
__device__ __forceinline__ void cex(unsigned& a, unsigned& b) {
    unsigned lo = min(a, b), hi = max(a, b);
    a = lo; b = hi;
}

__device__ __forceinline__ void sort4(unsigned* s) {
    cex(s[0], s[1]); cex(s[2], s[3]);
    cex(s[0], s[2]); cex(s[1], s[3]);
    cex(s[1], s[2]);
}

// v asc top-8; s asc 4 candidates -> v = 8 smallest of union, ascending.
// Identical to the validated merge8 with s padded to 8 by +inf (the 4
// min() ops against +inf are dropped); same 3-stage bitonic clean.
__device__ __forceinline__ void merge8_4(unsigned* v, const unsigned* s) {
    v[4] = min(v[4], s[3]); v[5] = min(v[5], s[2]);
    v[6] = min(v[6], s[1]); v[7] = min(v[7], s[0]);
    cex(v[0], v[4]); cex(v[1], v[5]); cex(v[2], v[6]); cex(v[3], v[7]);
    cex(v[0], v[2]); cex(v[1], v[3]); cex(v[4], v[6]); cex(v[5], v[7]);
    cex(v[0], v[1]); cex(v[2], v[3]); cex(v[4], v[5]); cex(v[6], v[7]);
}

// v asc top-8, s asc 8 candidates -> v = 8 smallest of union, ascending.
__device__ __forceinline__ void merge8(unsigned* v, const unsigned* s) {
#pragma unroll
    for (int i = 0; i < 8; i++) v[i] = min(v[i], s[7 - i]);
    cex(v[0], v[4]); cex(v[1], v[5]); cex(v[2], v[6]); cex(v[3], v[7]);
    cex(v[0], v[2]); cex(v[1], v[3]); cex(v[4], v[6]); cex(v[5], v[7]);
    cex(v[0], v[1]); cex(v[2], v[3]); cex(v[4], v[5]); cex(v[6], v[7]);
}

// ================= fused encoder (+ conv-side linear precomputes) =========
template<int FIN, int EXTRA>
__device__ void encode64_body(const float* __restrict__ x,
    const float* __restrict__ W1, const float* __restrict__ b1,
    const float* __restrict__ W2, const float* __restrict__ b2,
    const float* __restrict__ conv_W, const float* __restrict__ conv_b,
    float* __restrict__ enc, float* __restrict__ e1, float* __restrict__ e2,
    int blk, float* smem)
{
    float* sx  = smem;              // up to 64*30
    float* sW1 = sx + 64 * 30;      // up to 30*32
    float* sW2 = sW1 + 30 * 32;     // 1024
    float* sWe = sW2 + 1024;        // 1024
    float* sb1 = sWe + 1024;
    float* sb2 = sb1 + 32;
    float* sbe = sb2 + 32;
    float* sh  = sbe + 32;          // 2048
    int tid = threadIdx.x;
    for (int i = tid; i < FIN * 32; i += 256) sW1[i] = W1[i];
    for (int i = tid; i < 1024; i += 256) sW2[i] = W2[i];
    if (EXTRA == 1) for (int i = tid; i < 1024; i += 256) sWe[i] = conv_W[1024 + i];
    if (EXTRA == 2) for (int i = tid; i < 1024; i += 256) sWe[i] = conv_W[i] - conv_W[1024 + i];
    if (tid < 32) {
        sb1[tid] = b1[tid]; sb2[tid] = b2[tid];
        sbe[tid] = (EXTRA == 2) ? conv_b[tid] : 0.f;
    }
    size_t node0 = (size_t)blk * 64;
    for (int i = tid; i < 64 * FIN; i += 256) sx[i] = x[node0 * FIN + i];
    __syncthreads();
    int g = tid >> 5, c = tid & 31;
    float o[8];
#pragma unroll
    for (int j = 0; j < 8; j++) {
        int n = g * 8 + j;
        float a = sb1[c];
#pragma unroll
        for (int f = 0; f < FIN; f++) a = fmaf(sx[n * FIN + f], sW1[f * 32 + c], a);
        sh[n * 32 + c] = elu_f(a);
    }
    __syncthreads();
#pragma unroll
    for (int j = 0; j < 8; j++) {
        int n = g * 8 + j;
        float a = sb2[c];
#pragma unroll
        for (int k = 0; k < 32; k++) a = fmaf(sh[n * 32 + k], sW2[k * 32 + c], a);
        o[j] = elu_f(a);
        enc[(node0 + n) * 32 + c] = o[j];
    }
    if (EXTRA == 0) return;
    __syncthreads();
#pragma unroll
    for (int j = 0; j < 8; j++) sh[(g * 8 + j) * 32 + c] = o[j];
    __syncthreads();
#pragma unroll
    for (int j = 0; j < 8; j++) {
        int n = g * 8 + j;
        float a = sbe[c];
#pragma unroll
        for (int d = 0; d < 32; d++) a = fmaf(sh[n * 32 + d], sWe[d * 32 + c], a);
        size_t off = (node0 + n) * 32 + c;
        e1[off] = a;
        if (EXTRA == 2) e2[off] = a;
    }
}

// 4352 blocks: sv(256) | trk(2048) | pfc(2048)
__global__ __launch_bounds__(256) void encode_all_kernel(
    const float* __restrict__ x_sv, const float* __restrict__ x_trk, const float* __restrict__ x_pfc,
    const float* __restrict__ sv_W1, const float* __restrict__ sv_b1,
    const float* __restrict__ sv_W2, const float* __restrict__ sv_b2,
    const float* __restrict__ trk_W1, const float* __restrict__ trk_b1,
    const float* __restrict__ trk_W2, const float* __restrict__ trk_b2,
    const float* __restrict__ pfc_W1, const float* __restrict__ pfc_b1,
    const float* __restrict__ pfc_W2, const float* __restrict__ pfc_b2,
    const float* __restrict__ conv_W, const float* __restrict__ conv_b,
    float* __restrict__ sv_enc, float* __restrict__ trk_enc, float* __restrict__ pfc_enc,
    float* __restrict__ Y1, float* __restrict__ Y2,
    float* __restrict__ f1, float* __restrict__ f2)
{
    __shared__ float smem[64*30 + 30*32 + 1024 + 1024 + 96 + 2048];
    int bid = blockIdx.x;
    if (bid < 256)
        encode64_body<14, 1>(x_sv, sv_W1, sv_b1, sv_W2, sv_b2, conv_W, conv_b,
                             sv_enc, Y1, nullptr, bid, smem);
    else if (bid < 2304)
        encode64_body<30, 2>(x_trk, trk_W1, trk_b1, trk_W2, trk_b2, conv_W, conv_b,
                             trk_enc, f1, f2, bid - 256, smem);
    else
        encode64_body<10, 1>(x_pfc, pfc_W1, pfc_b1, pfc_W2, pfc_b2, conv_W, conv_b,
                             pfc_enc, Y2, nullptr, bid - 2304, smem);
}

// ================= kNN =====================================================
// LDS-pipe-bound phase: each thread now holds FOUR dst rows so every 16B
// src chunk broadcast-read from LDS feeds 4 accumulations (2 reads/pair
// instead of 4). 128 threads/block, 2 waves, ~215 VGPR.
__device__ __forceinline__ void load_xd(const float4* xi, v2f* xd) {
#pragma unroll
    for (int q = 0; q < 8; q++) {
        float4 v = xi[q];
        xd[2*q]   = (v2f){v.x, v.y};
        xd[2*q+1] = (v2f){v.z, v.w};
    }
}

__device__ __forceinline__ float norm32(const v2f* xd) {
    v2f A = {0.f, 0.f}, B = {0.f, 0.f};
#pragma unroll
    for (int q = 0; q < 8; q++) {
        A = __builtin_elementwise_fma(xd[2*q],   xd[2*q],   A);
        B = __builtin_elementwise_fma(xd[2*q+1], xd[2*q+1], B);
    }
    v2f S = A + B;
    return S.x + S.y;
}

template<int NR, int NT>
__device__ void stage_rows(const float* __restrict__ src_rows,
                           float4* s_src, float* s_nrm, int tid)
{
    const float4* s4 = (const float4*)src_rows;
    for (int i = tid; i < NR * 8; i += NT) s_src[i] = s4[i];
    __syncthreads();
    for (int s = tid; s < NR; s += NT) {
        float a = 0.f;
#pragma unroll
        for (int q = 0; q < 8; q++) {
            float4 v = s_src[s * 8 + q];
            a = fmaf(v.x, v.x, a); a = fmaf(v.y, v.y, a);
            a = fmaf(v.z, v.z, a); a = fmaf(v.w, v.w, a);
        }
        s_nrm[s] = a;
    }
    __syncthreads();
}

// 4-dst scan: dst-norms folded into accumulator init (dv >= 0 so raw-bit
// unsigned order == distance order); batch-4 candidate sort + bitonic merge.
template<int NR>
__device__ void knn_scan_core4(const float4* __restrict__ s_src, const float* __restrict__ s_nrm,
                               v2f (&xd)[4][16], const float* nh,
                               unsigned (&key)[4][8], int base)
{
    for (int s0 = 0; s0 < NR; s0 += 4) {
        unsigned cand[4][4];
#pragma unroll
        for (int j = 0; j < 4; j++) {
            int s = s0 + j;
            v2f a0[4], a1[4];
#pragma unroll
            for (int d = 0; d < 4; d++) {
                a0[d] = (v2f){nh[d], 0.f};
                a1[d] = (v2f){0.f, 0.f};
            }
#pragma unroll
            for (int q = 0; q < 8; q++) {
                float4 v = s_src[s * 8 + q];
                v2f vxy = {v.x, v.y};
                v2f vzw = {v.z, v.w};
#pragma unroll
                for (int d = 0; d < 4; d++) {
                    a0[d] = __builtin_elementwise_fma(xd[d][2*q],   vxy, a0[d]);
                    a1[d] = __builtin_elementwise_fma(xd[d][2*q+1], vzw, a1[d]);
                }
            }
            float nrm = s_nrm[s];
#pragma unroll
            for (int d = 0; d < 4; d++) {
                v2f S = a0[d] + a1[d];
                float dv = fmaf(-2.f, S.x + S.y, nrm);   // = |s|^2 + |d|^2 - 2<d,s>
                cand[d][j] = (__float_as_uint(dv) & 0xFFFFFE00u) | (unsigned)(base + s);
            }
        }
#pragma unroll
        for (int d = 0; d < 4; d++) { sort4(cand[d]); merge8_4(key[d], cand[d]); }
    }
}

// split part (128 rows): per-dst partial sorted top-8 keys (global idx in key)
// 128 threads; thread owns dsts {tid, tid+128, tid+256, tid+384}.
__device__ void knn_split_body4(const float* __restrict__ src, const float* __restrict__ dst,
                                unsigned* __restrict__ pkey,
                                int b, int part, float4* s_src, float* s_nrm)
{
    int tid = threadIdx.x;
    stage_rows<128, 128>(src + ((size_t)b * 512 + part * 128) * 32, s_src, s_nrm, tid);

    v2f xd[4][16];
    float nh[4];
#pragma unroll
    for (int d = 0; d < 4; d++) {
        load_xd((const float4*)(dst + ((size_t)b * 512 + d * 128 + tid) * 32), xd[d]);
        nh[d] = -0.5f * norm32(xd[d]);
    }

    unsigned key[4][8];
#pragma unroll
    for (int d = 0; d < 4; d++)
#pragma unroll
        for (int k = 0; k < 8; k++) key[d][k] = 0xFFFFFFFFu;

    knn_scan_core4<128>(s_src, s_nrm, xd, nh, key, part * 128);

#pragma unroll
    for (int d = 0; d < 4; d++) {
        unsigned* p = pkey + ((size_t)b * 512 + d * 128 + tid) * 32 + part * 8;
#pragma unroll
        for (int k = 0; k < 8; k++) p[k] = key[d][k];
    }
}

// conv1 small (64 src rows): final top-8 idx (u16) directly
__device__ void knn_small_body4(const float* __restrict__ src, const float* __restrict__ dst,
                                unsigned short* __restrict__ idx1_out,
                                int b, float4* s_src, float* s_nrm)
{
    int tid = threadIdx.x;
    stage_rows<64, 128>(src + (size_t)b * 64 * 32, s_src, s_nrm, tid);

    v2f xd[4][16];
    float nh[4];
#pragma unroll
    for (int d = 0; d < 4; d++) {
        load_xd((const float4*)(dst + ((size_t)b * 512 + d * 128 + tid) * 32), xd[d]);
        nh[d] = -0.5f * norm32(xd[d]);
    }

    unsigned key[4][8];
#pragma unroll
    for (int d = 0; d < 4; d++)
#pragma unroll
        for (int k = 0; k < 8; k++) key[d][k] = 0xFFFFFFFFu;

    knn_scan_core4<64>(s_src, s_nrm, xd, nh, key, 0);

#pragma unroll
    for (int d = 0; d < 4; d++) {
        int t = d * 128 + tid;
        unsigned int* o32 = (unsigned int*)(idx1_out + ((size_t)b * 512 + t) * 8);
#pragma unroll
        for (int k = 0; k < 4; k++)
            o32[k] = (key[d][2*k] & 511u) | ((key[d][2*k+1] & 511u) << 16);
    }
}

// knn12: 1280 blocks x 128 thr. conv2 split: bid<1024 (part=bid>>8, e=bid&255).
// conv1 small: tail blocks.
__global__ __launch_bounds__(128, 2) void knn12_kernel(
    const float* __restrict__ sv_enc, const float* __restrict__ trk_enc,
    const float* __restrict__ pfc_enc,
    unsigned short* __restrict__ idx1_out,
    unsigned* __restrict__ pkey)
{
    __shared__ float4 s_src[128 * 8];
    __shared__ float  s_nrm[128];
    int bid = blockIdx.x;
    if (bid < 1024) knn_split_body4(pfc_enc, trk_enc, pkey, bid & 255, bid >> 8, s_src, s_nrm);
    else            knn_small_body4(sv_enc, trk_enc, idx1_out, bid - 1024, s_src, s_nrm);
}

__global__ __launch_bounds__(128, 2) void knn3_kernel(
    const float* __restrict__ f1, const float* __restrict__ f2,
    unsigned* __restrict__ pkey)
{
    __shared__ float4 s_src[128 * 8];
    __shared__ float  s_nrm[128];
    int bid = blockIdx.x;
    knn_split_body4(f1, f2, pkey, bid & 255, bid >> 8, s_src, s_nrm);
}

// ================= gather helpers ==========================================
// merge 4 sorted partial key-lists (ascending part order) -> final 8 rows
__device__ __forceinline__ void merge_parts(const unsigned* __restrict__ pk_, int* rows)
{
    const uint4* pk = (const uint4*)pk_;
    uint4 a0 = pk[0], a1 = pk[1];
    unsigned v[8] = { a0.x, a0.y, a0.z, a0.w, a1.x, a1.y, a1.z, a1.w };
#pragma unroll
    for (int p = 1; p < 4; p++) {
        uint4 b0 = pk[2*p], b1 = pk[2*p+1];
        unsigned s[8] = { b0.x, b0.y, b0.z, b0.w, b1.x, b1.y, b1.z, b1.w };
        merge8(v, s);
    }
#pragma unroll
    for (int k = 0; k < 8; k++) rows[k] = (int)(v[k] & 511u);
}

__device__ __forceinline__ void maxgather(const float* __restrict__ Ybase,
                                          const int* rows, float4* m)
{
    const float4* Yb = (const float4*)Ybase;
    const float4* r0 = Yb + (size_t)rows[0] * 8;
#pragma unroll
    for (int q = 0; q < 8; q++) m[q] = r0[q];
#pragma unroll
    for (int k = 1; k < 8; k++) {
        const float4* rr = Yb + (size_t)rows[k] * 8;
#pragma unroll
        for (int q = 0; q < 8; q++) {
            float4 v = rr[q];
            m[q].x = fmaxf(m[q].x, v.x); m[q].y = fmaxf(m[q].y, v.y);
            m[q].z = fmaxf(m[q].z, v.z); m[q].w = fmaxf(m[q].w, v.w);
        }
    }
}

// g12: 1024 blocks. f holds Base (written by encode); in-place f=elu(f+maxY).
__global__ __launch_bounds__(256) void g12_kernel(
    const float* __restrict__ Y1, const unsigned short* __restrict__ idx1, float* __restrict__ f1,
    const float* __restrict__ Y2, const unsigned* __restrict__ pkey, float* __restrict__ f2)
{
    int bid = blockIdx.x;
    int tid = threadIdx.x;
    int rows[8];
    float* fp;
    const float* Yb;
    int t;
    if (bid < 512) {
        t = bid * 256 + tid;
        uint4 u = *(const uint4*)(idx1 + (size_t)t * 8);
        rows[0] = (int)(u.x & 0xffff); rows[1] = (int)(u.x >> 16);
        rows[2] = (int)(u.y & 0xffff); rows[3] = (int)(u.y >> 16);
        rows[4] = (int)(u.z & 0xffff); rows[5] = (int)(u.z >> 16);
        rows[6] = (int)(u.w & 0xffff); rows[7] = (int)(u.w >> 16);
        Yb = Y1 + (size_t)(t >> 9) * 64 * 32;
        fp = f1 + (size_t)t * 32;
    } else {
        t = (bid - 512) * 256 + tid;
        merge_parts(pkey + (size_t)t * 32, rows);
        Yb = Y2 + (size_t)(t >> 9) * 512 * 32;
        fp = f2 + (size_t)t * 32;
    }
    float4 m[8];
    maxgather(Yb, rows, m);
    float4* op = (float4*)fp;
#pragma unroll
    for (int q = 0; q < 8; q++) {
        float4 bv = op[q];
        float4 o;
        o.x = elu_f(bv.x + m[q].x); o.y = elu_f(bv.y + m[q].y);
        o.z = elu_f(bv.z + m[q].z); o.w = elu_f(bv.w + m[q].w);
        op[q] = o;
    }
}

// yb3: 4096 blocks: Y3 = f1@w2h (bid<2048) | B3 = f2@wd+bb
__global__ __launch_bounds__(256) void yb3_kernel(
    const float* __restrict__ f1, const float* __restrict__ f2,
    const float* __restrict__ conv_W, const float* __restrict__ conv_b,
    float* __restrict__ Y3, float* __restrict__ B3)
{
    __shared__ float sW[1024];
    __shared__ float sb[32];
    __shared__ float sx[8][32];
    int bid = blockIdx.x;
    int tid = threadIdx.x;
    int mode = (bid >= 2048);
    const float* X = mode ? f2 : f1;
    float* O = mode ? B3 : Y3;
    int rb = (mode ? bid - 2048 : bid) * 64;
    for (int i = tid; i < 1024; i += 256)
        sW[i] = mode ? (conv_W[i] - conv_W[1024 + i]) : conv_W[1024 + i];
    if (tid < 32) sb[tid] = mode ? conv_b[tid] : 0.f;
    int ln = tid >> 5, c = tid & 31;
    for (int p = 0; p < 8; p++) {
        __syncthreads();
        sx[ln][c] = X[(size_t)(rb + p * 8 + ln) * 32 + c];
        __syncthreads();
        float acc = sb[c];
#pragma unroll
        for (int d = 0; d < 32; d++) acc = fmaf(sx[ln][d], sW[d * 32 + c], acc);
        O[(size_t)(rb + p * 8 + ln) * 32 + c] = acc;
    }
}

// g3: 512 blocks. f3 rows in registers, reduced straight to pooled partials.
__global__ __launch_bounds__(256) void g3_kernel(
    const float* __restrict__ Y3, const float* __restrict__ B3,
    const unsigned* __restrict__ pkey,
    float* __restrict__ pool)
{
    __shared__ float sp[4][32];
    int bid = blockIdx.x;
    int tid = threadIdx.x, lane = tid & 63, wave = tid >> 6;
    int t = bid * 256 + tid;
    int e = t >> 9;
    int rows[8];
    merge_parts(pkey + (size_t)t * 32, rows);
    float4 m[8];
    maxgather(Y3 + (size_t)e * 512 * 32, rows, m);
    const float4* bp = (const float4*)(B3 + (size_t)t * 32);
    float4 r[8];
#pragma unroll
    for (int q = 0; q < 8; q++) {
        float4 bv = bp[q];
        r[q].x = elu_f(bv.x + m[q].x); r[q].y = elu_f(bv.y + m[q].y);
        r[q].z = elu_f(bv.z + m[q].z); r[q].w = elu_f(bv.w + m[q].w);
    }
    for (int off = 1; off < 64; off <<= 1) {
#pragma unroll
        for (int q = 0; q < 8; q++) {
            r[q].x += __shfl_xor(r[q].x, off);
            r[q].y += __shfl_xor(r[q].y, off);
            r[q].z += __shfl_xor(r[q].z, off);
            r[q].w += __shfl_xor(r[q].w, off);
        }
    }
    if (lane == 0) {
#pragma unroll
        for (int q = 0; q < 8; q++) {
            sp[wave][q*4+0] = r[q].x; sp[wave][q*4+1] = r[q].y;
            sp[wave][q*4+2] = r[q].z; sp[wave][q*4+3] = r[q].w;
        }
    }
    __syncthreads();
    if (tid < 32)
        pool[(size_t)bid * 32 + tid] = sp[0][tid] + sp[1][tid] + sp[2][tid] + sp[3][tid];
}

// final: 2 pooled partials per event + MLP + sigmoid + arange
__global__ __launch_bounds__(64) void final_kernel(
    const float* __restrict__ pool,
    const float* __restrict__ W1, const float* __restrict__ b1,
    const float* __restrict__ W2, const float* __restrict__ b2,
    float* __restrict__ outp)
{
    int b = blockIdx.x;
    int lane = threadIdx.x, c = lane & 31;
    __shared__ float sp[32];
    __shared__ float sh1[32];
    if (lane < 32)
        sp[c] = (pool[(size_t)(2*b) * 32 + c] + pool[(size_t)(2*b+1) * 32 + c]) * (1.0f / 512.0f);
    __syncthreads();
    if (lane < 32) {
        float h = b1[c];
#pragma unroll
        for (int d = 0; d < 32; d++) h = fmaf(sp[d], W1[d * 32 + c], h);
        sh1[c] = elu_f(h);
    }
    __syncthreads();
    if (lane == 0) {
        float o = b2[0];
#pragma unroll
        for (int d = 0; d < 32; d++) o = fmaf(sh1[d], W2[d], o);
        o = 1.f / (1.f + __expf(-o));
        outp[b] = o;
        outp[NB + b] = (float)b;
    }
}

extern "C" void kernel_launch(void* const* d_in, const int* in_sizes, int n_in,
                              void* d_out, int out_size, void* d_ws, size_t ws_size,
                              hipStream_t stream) {
    const float* x_sv  = (const float*)d_in[0];
    const float* x_trk = (const float*)d_in[1];
    const float* x_pfc = (const float*)d_in[2];
    const float* sv_W1  = (const float*)d_in[6];
    const float* sv_b1  = (const float*)d_in[7];
    const float* sv_W2  = (const float*)d_in[8];
    const float* sv_b2  = (const float*)d_in[9];
    const float* trk_W1 = (const float*)d_in[10];
    const float* trk_b1 = (const float*)d_in[11];
    const float* trk_W2 = (const float*)d_in[12];
    const float* trk_b2 = (const float*)d_in[13];
    const float* pfc_W1 = (const float*)d_in[14];
    const float* pfc_b1 = (const float*)d_in[15];
    const float* pfc_W2 = (const float*)d_in[16];
    const float* pfc_b2 = (const float*)d_in[17];
    const float* conv_W = (const float*)d_in[18];
    const float* conv_b = (const float*)d_in[19];
    const float* out_W1 = (const float*)d_in[20];
    const float* out_b1 = (const float*)d_in[21];
    const float* out_W2 = (const float*)d_in[22];
    const float* out_b2 = (const float*)d_in[23];

    float* ws = (float*)d_ws;
    const size_t SV_E  = (size_t)NB * 64 * 32;     //   524288
    const size_t TRK_E = (size_t)NB * 512 * 32;    //  4194304
    float* sv_enc  = ws;                           // pool aliases after knn12
    float* trk_enc = sv_enc + SV_E;                // B3 aliases after knn12
    float* pfc_enc = trk_enc + TRK_E;              // Y3 aliases after knn12
    float* f1      = pfc_enc + TRK_E;
    float* f2      = f1 + TRK_E;
    float* Y1      = f2 + TRK_E;                   // SV_E
    float* Y2      = Y1 + SV_E;                    // TRK_E
    unsigned* pkey = (unsigned*)(Y2 + TRK_E);      // NB*512*32 u32 (4 parts x 8)
    unsigned short* idx1 = (unsigned short*)(pkey + TRK_E);    // NB*512*8 u16
    float* Y3   = pfc_enc;   // pfc_enc dead after knn12
    float* B3   = trk_enc;   // trk_enc dead after knn12
    float* pool = sv_enc;    // sv_enc dead after knn12

    encode_all_kernel<<<4352, 256, 0, stream>>>(
        x_sv, x_trk, x_pfc,
        sv_W1, sv_b1, sv_W2, sv_b2,
        trk_W1, trk_b1, trk_W2, trk_b2,
        pfc_W1, pfc_b1, pfc_W2, pfc_b2,
        conv_W, conv_b,
        sv_enc, trk_enc, pfc_enc, Y1, Y2, f1, f2);

    knn12_kernel<<<1280, 128, 0, stream>>>(sv_enc, trk_enc, pfc_enc, idx1, pkey);
    g12_kernel<<<1024, 256, 0, stream>>>(Y1, idx1, f1, Y2, pkey, f2);

    yb3_kernel<<<4096, 256, 0, stream>>>(f1, f2, conv_W, conv_b, Y3, B3);
    knn3_kernel<<<1024, 128, 0, stream>>>(f1, f2, pkey);
    g3_kernel<<<512, 256, 0, stream>>>(Y3, B3, pkey, pool);

    final_kernel<<<NB, 64, 0, stream>>>(pool, out_W1, out_b1, out_W2, out_b2, (float*)d_out);
}